// Round 7
// baseline (459.499 us; speedup 1.0000x reference)
//
#include <hip/hip_runtime.h>
#include <math.h>

#define DDIM 1024
#define NCH 64
#define LSEQ 4096
#define NBATCH 8
#define NROWS (NBATCH * LSEQ)   // 32768
#define EPSF 1e-6f
#define NCK 64                  // chunks per sequence
#define CLEN 64                 // timesteps per chunk (NCK*CLEN == LSEQ)

__device__ __forceinline__ float softplusf(float v) {
    // matches jax.nn.softplus = log1p(exp(v)) with overflow guard
    return (v > 20.0f) ? v : log1pf(expf(v));
}

// ---------------- prep: WoT[n][d] = Wo[d][n] ----------------
__global__ void prep_kernel(const float* __restrict__ Wo, float* __restrict__ WoT) {
    int id = blockIdx.x * 256 + threadIdx.x;      // 65536 total
    int n = id >> 10;
    int d = id & (DDIM - 1);
    WoT[n * DDIM + d] = Wo[d * NCH + n];
}

// ---------------- proj: B_t/Delta GEMM + gating epilogue ----------------
// Block: 256 threads, 128 rows. Thread (rg = t>>3 in 0..31, ng = t&7 in 0..7)
// owns rows {rg + 32*i} (i<4) and cols {ng*8 .. ng*8+7}. K-chunks of 32.
#define MT_A 128
#define KT_A 32

__global__ __launch_bounds__(256) void proj_kernel(
        const float* __restrict__ x,
        const float* __restrict__ A_log,
        const float* __restrict__ WB,
        const float* __restrict__ bB,
        const float* __restrict__ Wd,
        const float* __restrict__ bd,
        float* __restrict__ dA_g,
        float* __restrict__ dB_g) {
    __shared__ float x_lds[MT_A][37];   // stride 37: bank = (5*row + k)%32, conflict-free
    __shared__ float w_lds[KT_A][68];   // cols 0..64 used (64 = Wd); 68 keeps 16B align
    __shared__ float delta_lds[MT_A];
    __shared__ float a_lds[NCH];
    __shared__ float bb_lds[NCH];

    const int t  = threadIdx.x;
    const int ng = t & 7;
    const int rg = t >> 3;
    const int R0 = blockIdx.x * MT_A;

    if (t < NCH) {
        a_lds[t]  = -softplusf(A_log[t]);
        bb_lds[t] = bB[t];
    }

    float acc[4][8];
    #pragma unroll
    for (int i = 0; i < 4; i++)
        #pragma unroll
        for (int j = 0; j < 8; j++) acc[i][j] = 0.0f;
    float dpart = 0.0f;

    for (int k0 = 0; k0 < DDIM; k0 += KT_A) {
        __syncthreads();
        // x tile 128x32 (4 passes of 32 rows, 128B segments per 8 lanes)
        #pragma unroll
        for (int p = 0; p < 4; p++) {
            int row = p * 32 + (t >> 3);
            int c   = (t & 7) * 4;
            const float4 v = *reinterpret_cast<const float4*>(&x[(size_t)(R0 + row) * DDIM + k0 + c]);
            x_lds[row][c + 0] = v.x; x_lds[row][c + 1] = v.y;
            x_lds[row][c + 2] = v.z; x_lds[row][c + 3] = v.w;
        }
        // W tile: WB 64x32 transposed into w_lds[k][n]
        #pragma unroll
        for (int p = 0; p < 2; p++) {
            int n = p * 32 + (t >> 3);
            int c = (t & 7) * 4;
            const float4 v = *reinterpret_cast<const float4*>(&WB[(size_t)n * DDIM + k0 + c]);
            w_lds[c + 0][n] = v.x; w_lds[c + 1][n] = v.y;
            w_lds[c + 2][n] = v.z; w_lds[c + 3][n] = v.w;
        }
        if (t < 8) {
            int c = t * 4;
            const float4 v = *reinterpret_cast<const float4*>(&Wd[k0 + c]);
            w_lds[c + 0][64] = v.x; w_lds[c + 1][64] = v.y;
            w_lds[c + 2][64] = v.z; w_lds[c + 3][64] = v.w;
        }
        __syncthreads();

        #pragma unroll 8
        for (int k = 0; k < KT_A; k++) {
            float xv[4];
            #pragma unroll
            for (int i = 0; i < 4; i++) xv[i] = x_lds[rg + 32 * i][k];
            const float4 w0 = *reinterpret_cast<const float4*>(&w_lds[k][ng * 8]);
            const float4 w1 = *reinterpret_cast<const float4*>(&w_lds[k][ng * 8 + 4]);
            const float wv[8] = {w0.x, w0.y, w0.z, w0.w, w1.x, w1.y, w1.z, w1.w};
            #pragma unroll
            for (int i = 0; i < 4; i++)
                #pragma unroll
                for (int j = 0; j < 8; j++)
                    acc[i][j] = fmaf(xv[i], wv[j], acc[i][j]);
        }
        // Delta partial: one row per thread t<128
        if (t < MT_A) {
            #pragma unroll 8
            for (int k = 0; k < KT_A; k++)
                dpart = fmaf(x_lds[t][k], w_lds[k][64], dpart);
        }
    }

    if (t < MT_A) delta_lds[t] = softplusf(dpart + bd[0]);
    __syncthreads();

    // epilogue: dA = exp(A*Delta); dB = (dA-1)/(A+eps) * (B_t + bB)
    #pragma unroll
    for (int i = 0; i < 4; i++) {
        const int row   = rg + 32 * i;
        const float dlt = delta_lds[row];
        float oA[8], oB[8];
        #pragma unroll
        for (int j = 0; j < 8; j++) {
            const int n   = ng * 8 + j;
            const float a = a_lds[n];
            const float dAv = expf(a * dlt);
            const float Bt  = acc[i][j] + bb_lds[n];
            oA[j] = dAv;
            oB[j] = (dAv - 1.0f) / (a + EPSF) * Bt;
        }
        float* pA = &dA_g[(size_t)(R0 + row) * NCH + ng * 8];
        float* pB = &dB_g[(size_t)(R0 + row) * NCH + ng * 8];
        *reinterpret_cast<float4*>(pA)     = make_float4(oA[0], oA[1], oA[2], oA[3]);
        *reinterpret_cast<float4*>(pA + 4) = make_float4(oA[4], oA[5], oA[6], oA[7]);
        *reinterpret_cast<float4*>(pB)     = make_float4(oB[0], oB[1], oB[2], oB[3]);
        *reinterpret_cast<float4*>(pB + 4) = make_float4(oB[4], oB[5], oB[6], oB[7]);
    }
}

// ---------------- chunked scan, 3 phases ----------------
// Chunks tile rows contiguously: chunk blk (= b*NCK + j) covers rows
// [blk*CLEN, blk*CLEN+CLEN). Per channel n:
//   C_t = E_blk * L_u  (L_0 = 1, L *= dA after use)  == reference shifted cumprod.

// K3: P[blk][n] = prod of dA over the chunk
__global__ __launch_bounds__(64) void chunkprod_kernel(
        const float* __restrict__ dA_g, float* __restrict__ P) {
    const int n = threadIdx.x;
    const int blk = blockIdx.x;                   // 0..NBATCH*NCK-1
    size_t base = (size_t)blk * CLEN * NCH + n;
    float p = 1.0f;
    #pragma unroll 8
    for (int u = 0; u < CLEN; u++) p *= dA_g[base + (size_t)u * NCH];
    P[(size_t)blk * NCH + n] = p;
}

// K4: exclusive product scan across chunks: E[b][j][n] = prod_{k<j} P[b][k][n]
__global__ __launch_bounds__(512) void stitch1_kernel(
        const float* __restrict__ P, float* __restrict__ E) {
    const int id = threadIdx.x;                   // 0..511 = b*64+n
    const int b = id >> 6, n = id & 63;
    size_t idx = (size_t)b * NCK * NCH + n;
    float e = 1.0f;
    for (int j = 0; j < NCK; j++) {
        E[idx + (size_t)j * NCH] = e;
        e *= P[idx + (size_t)j * NCH];
    }
}

// K5: Z[blk][n] = sum over chunk of dB/(E*L + eps)
__global__ __launch_bounds__(64) void chunkz_kernel(
        const float* __restrict__ dA_g, const float* __restrict__ dB_g,
        const float* __restrict__ E, float* __restrict__ Z) {
    const int n = threadIdx.x;
    const int blk = blockIdx.x;
    size_t base = (size_t)blk * CLEN * NCH + n;
    const float e = E[(size_t)blk * NCH + n];
    float L = 1.0f, zs = 0.0f;
    #pragma unroll 8
    for (int u = 0; u < CLEN; u++) {
        const float a  = dA_g[base + (size_t)u * NCH];
        const float bv = dB_g[base + (size_t)u * NCH];
        const float c  = e * L;
        zs += bv / (c + EPSF);
        L *= a;
    }
    Z[(size_t)blk * NCH + n] = zs;
}

// K6: exclusive sum scan across chunks: S[b][j][n] = sum_{k<j} Z[b][k][n]
__global__ __launch_bounds__(512) void stitch2_kernel(
        const float* __restrict__ Z, float* __restrict__ S) {
    const int id = threadIdx.x;
    const int b = id >> 6, n = id & 63;
    size_t idx = (size_t)b * NCK * NCH + n;
    float s = 0.0f;
    for (int j = 0; j < NCK; j++) {
        S[idx + (size_t)j * NCH] = s;
        s += Z[idx + (size_t)j * NCH];
    }
}

// K7: final pass, G = C^2 * (s_entry + local_s), written over dB in-place
__global__ __launch_bounds__(64) void chunkout_kernel(
        const float* __restrict__ dA_g, float* __restrict__ dBG,
        const float* __restrict__ E, const float* __restrict__ S) {
    const int n = threadIdx.x;
    const int blk = blockIdx.x;
    size_t base = (size_t)blk * CLEN * NCH + n;
    const float e = E[(size_t)blk * NCH + n];
    float L = 1.0f;
    float s = S[(size_t)blk * NCH + n];
    #pragma unroll 8
    for (int u = 0; u < CLEN; u++) {
        const float a  = dA_g[base + (size_t)u * NCH];
        const float bv = dBG [base + (size_t)u * NCH];
        const float c  = e * L;
        s += bv / (c + EPSF);                 // z = dB/(Ct+eps), inclusive
        dBG[base + (size_t)u * NCH] = c * c * s;   // Ct * X_state = Ct^2 * s
        L *= a;
    }
}

// ---------------- out: Y = G @ WoT + bo ----------------
#define MT_C 16
__global__ __launch_bounds__(256) void out_kernel(
        const float* __restrict__ G,
        const float* __restrict__ WoT,
        const float* __restrict__ bo,
        float* __restrict__ Y) {
    __shared__ float g_lds[NCH][20];    // transposed tile, 16B-aligned rows
    const int t  = threadIdx.x;
    const int R0 = blockIdx.x * MT_C;

    {
        int row = t >> 4;               // 0..15
        int n4  = (t & 15) * 4;
        const float4 v = *reinterpret_cast<const float4*>(&G[(size_t)(R0 + row) * NCH + n4]);
        g_lds[n4 + 0][row] = v.x; g_lds[n4 + 1][row] = v.y;
        g_lds[n4 + 2][row] = v.z; g_lds[n4 + 3][row] = v.w;
    }
    __syncthreads();

    const int d0 = t * 4;
    float acc[MT_C][4];
    #pragma unroll
    for (int r = 0; r < MT_C; r++)
        #pragma unroll
        for (int j = 0; j < 4; j++) acc[r][j] = 0.0f;

    for (int n = 0; n < NCH; n++) {
        const float4 wo = *reinterpret_cast<const float4*>(&WoT[n * DDIM + d0]);
        float g[MT_C];
        #pragma unroll
        for (int q = 0; q < 4; q++) {
            const float4 gv = *reinterpret_cast<const float4*>(&g_lds[n][q * 4]);
            g[q * 4 + 0] = gv.x; g[q * 4 + 1] = gv.y;
            g[q * 4 + 2] = gv.z; g[q * 4 + 3] = gv.w;
        }
        #pragma unroll
        for (int r = 0; r < MT_C; r++) {
            acc[r][0] = fmaf(g[r], wo.x, acc[r][0]);
            acc[r][1] = fmaf(g[r], wo.y, acc[r][1]);
            acc[r][2] = fmaf(g[r], wo.z, acc[r][2]);
            acc[r][3] = fmaf(g[r], wo.w, acc[r][3]);
        }
    }

    const float4 bov = *reinterpret_cast<const float4*>(&bo[d0]);
    #pragma unroll
    for (int r = 0; r < MT_C; r++) {
        float4 o;
        o.x = acc[r][0] + bov.x; o.y = acc[r][1] + bov.y;
        o.z = acc[r][2] + bov.z; o.w = acc[r][3] + bov.w;
        *reinterpret_cast<float4*>(&Y[(size_t)(R0 + r) * DDIM + d0]) = o;
    }
}

extern "C" void kernel_launch(void* const* d_in, const int* in_sizes, int n_in,
                              void* d_out, int out_size, void* d_ws, size_t ws_size,
                              hipStream_t stream) {
    const float* x     = (const float*)d_in[0];
    const float* A_log = (const float*)d_in[1];
    const float* WB    = (const float*)d_in[2];
    const float* bB    = (const float*)d_in[3];
    // d_in[4] = WC, d_in[5] = bC : dead in the reference
    const float* Wd    = (const float*)d_in[6];
    const float* bd    = (const float*)d_in[7];
    const float* Wo    = (const float*)d_in[8];
    const float* bo    = (const float*)d_in[9];
    float* Y = (float*)d_out;

    float* dA_g = (float*)d_ws;                    // NROWS*NCH
    float* dBG  = dA_g + (size_t)NROWS * NCH;      // NROWS*NCH (dB, then G in-place)
    float* WoT  = dBG  + (size_t)NROWS * NCH;      // NCH*DDIM
    float* P    = WoT  + (size_t)NCH * DDIM;       // NBATCH*NCK*NCH
    float* E    = P    + (size_t)NBATCH * NCK * NCH;
    float* Z    = E    + (size_t)NBATCH * NCK * NCH;
    float* S    = Z    + (size_t)NBATCH * NCK * NCH;

    const int NCHUNKS = NBATCH * NCK;              // 512

    prep_kernel<<<dim3(256), dim3(256), 0, stream>>>(Wo, WoT);
    proj_kernel<<<dim3(NROWS / MT_A), dim3(256), 0, stream>>>(
        x, A_log, WB, bB, Wd, bd, dA_g, dBG);
    chunkprod_kernel<<<dim3(NCHUNKS), dim3(64), 0, stream>>>(dA_g, P);
    stitch1_kernel<<<dim3(1), dim3(512), 0, stream>>>(P, E);
    chunkz_kernel<<<dim3(NCHUNKS), dim3(64), 0, stream>>>(dA_g, dBG, E, Z);
    stitch2_kernel<<<dim3(1), dim3(512), 0, stream>>>(Z, S);
    chunkout_kernel<<<dim3(NCHUNKS), dim3(64), 0, stream>>>(dA_g, dBG, E, S);
    out_kernel<<<dim3(NROWS / MT_C), dim3(256), 0, stream>>>(dBG, WoT, bo, Y);
}

// Round 8
// 409.293 us; speedup vs baseline: 1.1227x; 1.1227x over previous
//
#include <hip/hip_runtime.h>
#include <math.h>

#define DDIM 1024
#define NCH 64
#define LSEQ 4096
#define NBATCH 8
#define NROWS (NBATCH * LSEQ)   // 32768
#define EPSF 1e-6f
#define NCK 64                  // chunks per sequence
#define CLEN 64                 // timesteps per chunk

__device__ __forceinline__ float softplusf(float v) {
    return (v > 20.0f) ? v : log1pf(expf(v));
}

// ---------------- prep: WoT[n][d] = Wo[d][n] ----------------
__global__ void prep_kernel(const float* __restrict__ Wo, float* __restrict__ WoT) {
    int id = blockIdx.x * 256 + threadIdx.x;
    int n = id >> 10;
    int d = id & (DDIM - 1);
    WoT[n * DDIM + d] = Wo[d * NCH + n];
}

// ---------------- proj2: K-split GEMM, W streamed from L2, partials to 2 buffers ----
// Grid = (NROWS/128)*2.  rt = bid>>1 (row tile), ks = bid&1 (K half: 512 each).
// Block 256 thr: tr = t&31, tc = t>>5. Thread tile rows {tr+32i}, cols {tc*8..+7}.
#define MT 128
#define KSPL 2
#define KRNG (DDIM / KSPL)      // 512
#define SUBK 32

__global__ __launch_bounds__(256, 2) void proj2_kernel(
        const float* __restrict__ x,
        const float* __restrict__ WB,
        const float* __restrict__ Wd,
        float* __restrict__ Bt0, float* __restrict__ Bt1,
        float* __restrict__ De0, float* __restrict__ De1) {
    __shared__ float x_lds[MT][36];   // stride 36: 16B-aligned rows for b128 reads
    const int t  = threadIdx.x;
    const int tr = t & 31;
    const int tc = t >> 5;
    const int rt = blockIdx.x >> 1;
    const int ks = blockIdx.x & 1;
    const int R0 = rt * MT;
    const int kb0 = ks * KRNG;

    float acc[4][8];
    #pragma unroll
    for (int i = 0; i < 4; i++)
        #pragma unroll
        for (int j = 0; j < 8; j++) acc[i][j] = 0.0f;
    float dpart = 0.0f;

    for (int kk = 0; kk < KRNG; kk += SUBK) {
        const int kb = kb0 + kk;
        __syncthreads();
        // stage x tile 128x32, float4 coalesced
        #pragma unroll
        for (int p = 0; p < 4; p++) {
            const int row = p * 32 + (t >> 3);
            const int c   = (t & 7) * 4;
            const float4 v = *reinterpret_cast<const float4*>(
                &x[(size_t)(R0 + row) * DDIM + kb + c]);
            *reinterpret_cast<float4*>(&x_lds[row][c]) = v;
        }
        __syncthreads();

        // Delta partial (rows == threads t<128); Wd scalar loads are wave-uniform (L1-hot)
        if (t < MT) {
            #pragma unroll 8
            for (int k = 0; k < SUBK; k++)
                dpart = fmaf(x_lds[t][k], Wd[kb + k], dpart);
        }

        // main FMA: 4-k steps; W from global (L2-resident), x from LDS b128
        #pragma unroll
        for (int k4 = 0; k4 < SUBK / 4; k4++) {
            float4 wv[8];
            #pragma unroll
            for (int j = 0; j < 8; j++)
                wv[j] = *reinterpret_cast<const float4*>(
                    &WB[(size_t)(tc * 8 + j) * DDIM + kb + k4 * 4]);
            float4 xv[4];
            #pragma unroll
            for (int i = 0; i < 4; i++)
                xv[i] = *reinterpret_cast<const float4*>(&x_lds[tr + 32 * i][k4 * 4]);
            #pragma unroll
            for (int i = 0; i < 4; i++)
                #pragma unroll
                for (int j = 0; j < 8; j++) {
                    acc[i][j] = fmaf(xv[i].x, wv[j].x, acc[i][j]);
                    acc[i][j] = fmaf(xv[i].y, wv[j].y, acc[i][j]);
                    acc[i][j] = fmaf(xv[i].z, wv[j].z, acc[i][j]);
                    acc[i][j] = fmaf(xv[i].w, wv[j].w, acc[i][j]);
                }
        }
    }

    float* Bt = ks ? Bt1 : Bt0;
    #pragma unroll
    for (int i = 0; i < 4; i++) {
        const size_t base = (size_t)(R0 + tr + 32 * i) * NCH + tc * 8;
        *reinterpret_cast<float4*>(&Bt[base])     = make_float4(acc[i][0], acc[i][1], acc[i][2], acc[i][3]);
        *reinterpret_cast<float4*>(&Bt[base + 4]) = make_float4(acc[i][4], acc[i][5], acc[i][6], acc[i][7]);
    }
    if (t < MT) (ks ? De1 : De0)[R0 + t] = dpart;
}

// ---------------- gate: sum partials + softplus/exp epilogue ----------------
// grid = NROWS/4, block 256: t = n + 64*r4. Writes dA_g; dBG (=Bt0) in place.
__global__ __launch_bounds__(256) void gate_kernel(
        const float* __restrict__ A_log, const float* __restrict__ bB,
        const float* __restrict__ bd,
        const float* __restrict__ De0, const float* __restrict__ De1,
        float* __restrict__ dA_g,       // also Bt1 partial (read first!)
        float* __restrict__ dBG) {      // Bt0 partial -> dB in place
    const int t   = threadIdx.x;
    const int n   = t & 63;
    const int row = blockIdx.x * 4 + (t >> 6);
    const size_t idx = (size_t)row * NCH + n;
    const float a   = -softplusf(A_log[n]);
    const float dlt = softplusf(De0[row] + De1[row] + bd[0]);
    const float Btv = dBG[idx] + dA_g[idx] + bB[n];
    const float dAv = expf(a * dlt);
    const float dBv = (dAv - 1.0f) / (a + EPSF) * Btv;
    dA_g[idx] = dAv;
    dBG[idx]  = dBv;
}

// ---------------- chunked scan, 3 phases ----------------
__global__ __launch_bounds__(64) void chunkprod_kernel(
        const float* __restrict__ dA_g, float* __restrict__ P) {
    const int n = threadIdx.x;
    const int blk = blockIdx.x;
    size_t base = (size_t)blk * CLEN * NCH + n;
    float p = 1.0f;
    #pragma unroll 8
    for (int u = 0; u < CLEN; u++) p *= dA_g[base + (size_t)u * NCH];
    P[(size_t)blk * NCH + n] = p;
}

__global__ __launch_bounds__(512) void stitch1_kernel(
        const float* __restrict__ P, float* __restrict__ E) {
    const int id = threadIdx.x;
    const int b = id >> 6, n = id & 63;
    size_t idx = (size_t)b * NCK * NCH + n;
    float e = 1.0f;
    for (int j0 = 0; j0 < NCK; j0 += 8) {
        float p8[8];
        #pragma unroll
        for (int u = 0; u < 8; u++) p8[u] = P[idx + (size_t)(j0 + u) * NCH];
        #pragma unroll
        for (int u = 0; u < 8; u++) {
            E[idx + (size_t)(j0 + u) * NCH] = e;
            e *= p8[u];
        }
    }
}

__global__ __launch_bounds__(64) void chunkz_kernel(
        const float* __restrict__ dA_g, const float* __restrict__ dB_g,
        const float* __restrict__ E, float* __restrict__ Z) {
    const int n = threadIdx.x;
    const int blk = blockIdx.x;
    size_t base = (size_t)blk * CLEN * NCH + n;
    const float e = E[(size_t)blk * NCH + n];
    float L = 1.0f, zs = 0.0f;
    #pragma unroll 8
    for (int u = 0; u < CLEN; u++) {
        const float a  = dA_g[base + (size_t)u * NCH];
        const float bv = dB_g[base + (size_t)u * NCH];
        const float c  = e * L;
        zs += bv / (c + EPSF);
        L *= a;
    }
    Z[(size_t)blk * NCH + n] = zs;
}

__global__ __launch_bounds__(512) void stitch2_kernel(
        const float* __restrict__ Z, float* __restrict__ S) {
    const int id = threadIdx.x;
    const int b = id >> 6, n = id & 63;
    size_t idx = (size_t)b * NCK * NCH + n;
    float s = 0.0f;
    for (int j0 = 0; j0 < NCK; j0 += 8) {
        float z8[8];
        #pragma unroll
        for (int u = 0; u < 8; u++) z8[u] = Z[idx + (size_t)(j0 + u) * NCH];
        #pragma unroll
        for (int u = 0; u < 8; u++) {
            S[idx + (size_t)(j0 + u) * NCH] = s;
            s += z8[u];
        }
    }
}

__global__ __launch_bounds__(64) void chunkout_kernel(
        const float* __restrict__ dA_g, float* __restrict__ dBG,
        const float* __restrict__ E, const float* __restrict__ S) {
    const int n = threadIdx.x;
    const int blk = blockIdx.x;
    size_t base = (size_t)blk * CLEN * NCH + n;
    const float e = E[(size_t)blk * NCH + n];
    float L = 1.0f;
    float s = S[(size_t)blk * NCH + n];
    #pragma unroll 8
    for (int u = 0; u < CLEN; u++) {
        const float a  = dA_g[base + (size_t)u * NCH];
        const float bv = dBG [base + (size_t)u * NCH];
        const float c  = e * L;
        s += bv / (c + EPSF);
        dBG[base + (size_t)u * NCH] = c * c * s;
        L *= a;
    }
}

// ---------------- out2: Y = G @ WoT + bo, 8x8/thread, WoT from L2 ----------------
// Block tile 32 rows x 512 cols; grid = (NROWS/32)*2.
// t: tc = t&63 (col group, 8 cols), tr = t>>6 (row group, 8 rows). Wave-uniform tr.
__global__ __launch_bounds__(256, 4) void out2_kernel(
        const float* __restrict__ G,
        const float* __restrict__ WoT,
        const float* __restrict__ bo,
        float* __restrict__ Y) {
    __shared__ float g_lds[NCH][36];   // [n][row], stride 36 (16B-aligned)
    const int t  = threadIdx.x;
    const int tc = t & 63;
    const int tr = t >> 6;
    const int R0 = (blockIdx.x >> 1) * 32;
    const int D0 = (blockIdx.x & 1) * 512;

    {   // stage G 32x64 transposed
        const int grow = t >> 3;
        const int gn0  = (t & 7) * 8;
        const float4 a0 = *reinterpret_cast<const float4*>(&G[(size_t)(R0 + grow) * NCH + gn0]);
        const float4 a1 = *reinterpret_cast<const float4*>(&G[(size_t)(R0 + grow) * NCH + gn0 + 4]);
        g_lds[gn0 + 0][grow] = a0.x; g_lds[gn0 + 1][grow] = a0.y;
        g_lds[gn0 + 2][grow] = a0.z; g_lds[gn0 + 3][grow] = a0.w;
        g_lds[gn0 + 4][grow] = a1.x; g_lds[gn0 + 5][grow] = a1.y;
        g_lds[gn0 + 6][grow] = a1.z; g_lds[gn0 + 7][grow] = a1.w;
    }
    __syncthreads();

    float acc[8][8];
    #pragma unroll
    for (int i = 0; i < 8; i++)
        #pragma unroll
        for (int j = 0; j < 8; j++) acc[i][j] = 0.0f;

    const size_t wcol = (size_t)D0 + tc * 8;
    for (int n = 0; n < NCH; n++) {
        const float4 g0 = *reinterpret_cast<const float4*>(&g_lds[n][tr * 8]);
        const float4 g1 = *reinterpret_cast<const float4*>(&g_lds[n][tr * 8 + 4]);
        const float4 w0 = *reinterpret_cast<const float4*>(&WoT[(size_t)n * DDIM + wcol]);
        const float4 w1 = *reinterpret_cast<const float4*>(&WoT[(size_t)n * DDIM + wcol + 4]);
        const float ga[8] = {g0.x, g0.y, g0.z, g0.w, g1.x, g1.y, g1.z, g1.w};
        const float wa[8] = {w0.x, w0.y, w0.z, w0.w, w1.x, w1.y, w1.z, w1.w};
        #pragma unroll
        for (int i = 0; i < 8; i++)
            #pragma unroll
            for (int j = 0; j < 8; j++)
                acc[i][j] = fmaf(ga[i], wa[j], acc[i][j]);
    }

    const float4 b0 = *reinterpret_cast<const float4*>(&bo[wcol]);
    const float4 b1 = *reinterpret_cast<const float4*>(&bo[wcol + 4]);
    #pragma unroll
    for (int i = 0; i < 8; i++) {
        const size_t yb = (size_t)(R0 + tr * 8 + i) * DDIM + wcol;
        *reinterpret_cast<float4*>(&Y[yb]) =
            make_float4(acc[i][0] + b0.x, acc[i][1] + b0.y, acc[i][2] + b0.z, acc[i][3] + b0.w);
        *reinterpret_cast<float4*>(&Y[yb + 4]) =
            make_float4(acc[i][4] + b1.x, acc[i][5] + b1.y, acc[i][6] + b1.z, acc[i][7] + b1.w);
    }
}

extern "C" void kernel_launch(void* const* d_in, const int* in_sizes, int n_in,
                              void* d_out, int out_size, void* d_ws, size_t ws_size,
                              hipStream_t stream) {
    const float* x     = (const float*)d_in[0];
    const float* A_log = (const float*)d_in[1];
    const float* WB    = (const float*)d_in[2];
    const float* bB    = (const float*)d_in[3];
    const float* Wd    = (const float*)d_in[6];
    const float* bd    = (const float*)d_in[7];
    const float* Wo    = (const float*)d_in[8];
    const float* bo    = (const float*)d_in[9];
    float* Y = (float*)d_out;

    float* dA_g = (float*)d_ws;                    // NROWS*NCH  (Bt partial 1, then dA)
    float* dBG  = dA_g + (size_t)NROWS * NCH;      // NROWS*NCH  (Bt partial 0 -> dB -> G)
    float* WoT  = dBG  + (size_t)NROWS * NCH;      // NCH*DDIM
    float* P    = WoT  + (size_t)NCH * DDIM;       // NBATCH*NCK*NCH
    float* E    = P    + (size_t)NBATCH * NCK * NCH;
    float* Z    = E    + (size_t)NBATCH * NCK * NCH;
    float* S    = Z    + (size_t)NBATCH * NCK * NCH;
    float* De0  = S    + (size_t)NBATCH * NCK * NCH;   // NROWS
    float* De1  = De0  + (size_t)NROWS;                // NROWS

    const int NCHUNKS = NBATCH * NCK;              // 512

    prep_kernel<<<dim3(256), dim3(256), 0, stream>>>(Wo, WoT);
    proj2_kernel<<<dim3((NROWS / MT) * KSPL), dim3(256), 0, stream>>>(
        x, WB, Wd, dBG, dA_g, De0, De1);
    gate_kernel<<<dim3(NROWS / 4), dim3(256), 0, stream>>>(
        A_log, bB, bd, De0, De1, dA_g, dBG);
    chunkprod_kernel<<<dim3(NCHUNKS), dim3(64), 0, stream>>>(dA_g, P);
    stitch1_kernel<<<dim3(1), dim3(512), 0, stream>>>(P, E);
    chunkz_kernel<<<dim3(NCHUNKS), dim3(64), 0, stream>>>(dA_g, dBG, E, Z);
    stitch2_kernel<<<dim3(1), dim3(512), 0, stream>>>(Z, S);
    chunkout_kernel<<<dim3(NCHUNKS), dim3(64), 0, stream>>>(dA_g, dBG, E, S);
    out2_kernel<<<dim3((NROWS / 32) * 2), dim3(256), 0, stream>>>(dBG, WoT, bo, Y);
}